// Round 21
// baseline (468.206 us; speedup 1.0000x reference)
//
#include <hip/hip_runtime.h>
#include <hip/hip_bf16.h>
#include <math.h>

#define NODES 50000
#define EDGES 800000
#define EP    850000      // EDGES + NODES self loops
#define INCH  64
#define HIDD  96
#define NHEAD 4
#define CHD   24
#define NLAY  4
#define NGRF  1024
#define BNEPS 1e-5f
#define NB    49          // ceil(NODES/1024)
#define NSH   4           // pooled shards (blockIdx&3 -> XCD locality)

typedef short  bf16x8 __attribute__((ext_vector_type(8)));   // 8 bf16 (4 VGPRs)
typedef float  f32x4  __attribute__((ext_vector_type(4)));   // MFMA accumulator

__device__ __forceinline__ float elu1(float v) { return v > 0.f ? v : __expf(v) - 1.f; }

__device__ __forceinline__ unsigned short f2bf(float f) {   // RNE, matches HW
    unsigned u = __float_as_uint(f);
    return (unsigned short)((u + 0x7fffu + ((u >> 16) & 1u)) >> 16);
}

__device__ __forceinline__ float rl_f(float v, int l) {     // readlane broadcast (uniform l)
    return __int_as_float(__builtin_amdgcn_readlane(__float_as_int(v), l));
}

__device__ __forceinline__ float bnorm(float a, const float* __restrict__ bg,
                                       const float* __restrict__ rm, const float* __restrict__ rv,
                                       const float* __restrict__ gamma, const float* __restrict__ beta,
                                       int ch) {
    float hn = a + bg[ch];
    return (hn - rm[ch]) / sqrtf(rv[ch] + BNEPS) * gamma[ch] + beta[ch];
}

__device__ __forceinline__ void edge_sd(int e, const int* __restrict__ S,
                                        const int* __restrict__ D, int& s, int& d) {
    if (e < EDGES) { s = S[e]; d = D[e]; } else { s = e - EDGES; d = s; }
}

// ---------------- CSR build ----------------

__global__ __launch_bounds__(256) void k_count(const int* __restrict__ S, const int* __restrict__ D,
                                               int* __restrict__ cnt) {
    int e = blockIdx.x * blockDim.x + threadIdx.x;
    if (e >= EP) return;
    int s, d; edge_sd(e, S, D, s, d);
    atomicAdd(&cnt[d], 1);
}

__global__ __launch_bounds__(1024) void k_scan1(const int* __restrict__ cnt,
                                                int* __restrict__ off, int* __restrict__ bsum) {
    __shared__ int sd[1024];
    int t = threadIdx.x;
    int i = blockIdx.x * 1024 + t;
    int v = (i < NODES) ? cnt[i] : 0;
    sd[t] = v; __syncthreads();
    for (int o = 1; o < 1024; o <<= 1) {
        int tv = (t >= o) ? sd[t - o] : 0;
        __syncthreads();
        sd[t] += tv; __syncthreads();
    }
    if (i < NODES) off[i] = sd[t] - v;           // exclusive within block
    if (t == 1023) bsum[blockIdx.x] = sd[1023];
}

__global__ __launch_bounds__(1024) void k_scan3m(int* __restrict__ off, const int* __restrict__ bsum,
                                                 int* __restrict__ cursor) {
    int carry = 0;
    for (int b = 0; b < blockIdx.x; ++b) carry += bsum[b];   // uniform s_loads
    int i = blockIdx.x * 1024 + threadIdx.x;
    if (i < NODES) {
        int o = off[i] + carry;
        off[i] = o;
        cursor[i] = o;
    }
    if (i == 0) off[NODES] = EP;
}

__global__ __launch_bounds__(256) void k_scatter(const int* __restrict__ S, const int* __restrict__ D,
                                                 int* __restrict__ cursor, int* __restrict__ csr_src) {
    int e = blockIdx.x * blockDim.x + threadIdx.x;
    if (e >= EP) return;
    int s, d; edge_sd(e, S, D, s, d);
    int pos = atomicAdd(&cursor[d], 1);
    csr_src[pos] = s;
}

// ---------------- layer 0, all-MFMA (also zeros sharded pooled) ----------------

__global__ __launch_bounds__(256) void k_in0(const float* __restrict__ x,
                                             const float* __restrict__ W_in,
                                             const float* __restrict__ b_in,
                                             const float* __restrict__ Wg0,
                                             const float* __restrict__ asrc,
                                             const float* __restrict__ adst,
                                             float* __restrict__ h,
                                             unsigned* __restrict__ hpb,
                                             float* __restrict__ as_,
                                             float* __restrict__ ad_,
                                             float* __restrict__ pooled_all) {
    __shared__ __align__(16) unsigned short WB[3 * 6 * 64 * 8];  // 18 KB (W_in uses 12 KB)
    __shared__ float outT[4][16][97];                            // 24.25 KB, wave-private tiles
    int tid = threadIdx.x;
    int lane = tid & 63;
    int w = tid >> 6;

    // zero sharded pooled (grid-stride; completes before k_edge in stream order)
    for (size_t i = (size_t)blockIdx.x * 256 + tid; i < (size_t)NLAY * NSH * NGRF * HIDD;
         i += (size_t)gridDim.x * 256)
        pooled_all[i] = 0.f;

    // stage W_in -> fragment layout (K=64 -> frags 0..11)
    for (int idx = tid; idx < INCH * HIDD; idx += 256) {
        int k = idx / HIDD, col = idx - k * HIDD;
        int kb = k >> 5, lg = (k & 31) >> 3, i = k & 7;
        int nt = col >> 4, cl = col & 15;
        WB[(((kb * 6) + nt) * 64 + (lg * 16 + cl)) * 8 + i] = f2bf(W_in[idx]);
    }
    __syncthreads();

    bf16x8 bf1[12];
#pragma unroll
    for (int f = 0; f < 12; ++f)
        bf1[f] = *(const bf16x8*)&WB[(f * 64 + lane) * 8];

    int nodeBase = blockIdx.x * 64 + w * 16;
    int arow = nodeBase + (lane & 15);
    int arowc = min(arow, NODES - 1);

    // ---- stage 1: x @ W_in ----
    {
        f32x4 acc[6];
#pragma unroll
        for (int n = 0; n < 6; ++n) { acc[n][0]=0.f; acc[n][1]=0.f; acc[n][2]=0.f; acc[n][3]=0.f; }
#pragma unroll
        for (int kb = 0; kb < 2; ++kb) {
            const float* ap = x + (size_t)arowc * INCH + kb * 32 + (lane >> 4) * 8;
            float4 u0 = *(const float4*)ap;
            float4 u1 = *(const float4*)(ap + 4);
            bf16x8 af;
            af[0]=(short)f2bf(u0.x); af[1]=(short)f2bf(u0.y); af[2]=(short)f2bf(u0.z); af[3]=(short)f2bf(u0.w);
            af[4]=(short)f2bf(u1.x); af[5]=(short)f2bf(u1.y); af[6]=(short)f2bf(u1.z); af[7]=(short)f2bf(u1.w);
#pragma unroll
            for (int nt = 0; nt < 6; ++nt)
                acc[nt] = __builtin_amdgcn_mfma_f32_16x16x32_bf16(af, bf1[kb * 6 + nt], acc[nt], 0, 0, 0);
        }
#pragma unroll
        for (int nt = 0; nt < 6; ++nt) {
            int col = nt * 16 + (lane & 15);
            float b = b_in[col];
#pragma unroll
            for (int r = 0; r < 4; ++r)
                outT[w][(lane >> 4) * 4 + r][col] = elu1(acc[nt][r] + b);
        }
    }
    __syncthreads();                    // all waves done reading WB (bf1 in regs)

    // restage Wg0 -> fragment layout (frags 0..17)
    for (int idx = tid; idx < HIDD * HIDD; idx += 256) {
        int k = idx / HIDD, col = idx - k * HIDD;
        int kb = k >> 5, lg = (k & 31) >> 3, i = k & 7;
        int nt = col >> 4, cl = col & 15;
        WB[(((kb * 6) + nt) * 64 + (lg * 16 + cl)) * 8 + i] = f2bf(Wg0[idx]);
    }
    __syncthreads();

    bf16x8 bf2[18];
#pragma unroll
    for (int f = 0; f < 18; ++f)
        bf2[f] = *(const bf16x8*)&WB[(f * 64 + lane) * 8];

    // write h to global (coalesced; own outT region, wave-ordered)
    {
        int nl = lane >> 2, part = lane & 3;
        int noden = nodeBase + nl;
        if (noden < NODES) {
            float* hw = h + (size_t)noden * HIDD + part * 24;
            const float* row = &outT[w][nl][part * 24];
#pragma unroll
            for (int t = 0; t < 6; ++t)
                ((float4*)hw)[t] = *(const float4*)&row[t * 4];
        }
    }

    // ---- stage 2: h @ Wg0 (A from own outT region) ----
    f32x4 acc2[6];
#pragma unroll
    for (int n = 0; n < 6; ++n) { acc2[n][0]=0.f; acc2[n][1]=0.f; acc2[n][2]=0.f; acc2[n][3]=0.f; }
#pragma unroll
    for (int kb = 0; kb < 3; ++kb) {
        const float* ap = &outT[w][lane & 15][kb * 32 + (lane >> 4) * 8];
        bf16x8 af;
#pragma unroll
        for (int i = 0; i < 8; ++i) af[i] = (short)f2bf(ap[i]);
#pragma unroll
        for (int nt = 0; nt < 6; ++nt)
            acc2[nt] = __builtin_amdgcn_mfma_f32_16x16x32_bf16(af, bf2[kb * 6 + nt], acc2[nt], 0, 0, 0);
    }
#pragma unroll
    for (int nt = 0; nt < 6; ++nt)
#pragma unroll
        for (int r = 0; r < 4; ++r)
            outT[w][(lane >> 4) * 4 + r][nt * 16 + (lane & 15)] = acc2[nt][r];

    int nl = lane >> 2, head = lane & 3;
    int node = nodeBase + nl;
    if (node < NODES) {
        const float* row = &outT[w][nl][head * CHD];
        unsigned* orow = hpb + (size_t)node * (HIDD / 2) + head * (CHD / 2);
#pragma unroll
        for (int t = 0; t < CHD / 2; ++t)
            orow[t] = (unsigned)f2bf(row[2 * t]) | ((unsigned)f2bf(row[2 * t + 1]) << 16);
        const float* s = asrc + head * CHD;
        const float* d = adst + head * CHD;
        float sa = 0.f, da = 0.f;
#pragma unroll
        for (int j = 0; j < CHD; ++j) { sa = fmaf(row[j], s[j], sa); da = fmaf(row[j], d[j], da); }
        as_[node * NHEAD + head] = sa;
        ad_[node * NHEAD + head] = da;
    }
}

// ---------------- per-layer proj via MFMA (layers 1..3) ----------------

__global__ __launch_bounds__(256) void k_proj(const float* __restrict__ h,
                                              const float* __restrict__ W,
                                              const float* __restrict__ asrc,
                                              const float* __restrict__ adst,
                                              unsigned* __restrict__ hpb,   // [N][48] packed bf16x2
                                              float* __restrict__ as_,
                                              float* __restrict__ ad_) {
    __shared__ __align__(16) unsigned short WB[3 * 6 * 64 * 8];  // 18 KB, fragment layout
    __shared__ float outT[4][16][97];                            // 24.25 KB, padded rows
    int tid = threadIdx.x;
    int lane = tid & 63;
    int w = tid >> 6;

    for (int idx = tid; idx < HIDD * HIDD; idx += 256) {
        int k = idx / HIDD, col = idx - k * HIDD;
        int kb = k >> 5, lg = (k & 31) >> 3, i = k & 7;
        int nt = col >> 4, cl = col & 15;
        WB[(((kb * 6) + nt) * 64 + (lg * 16 + cl)) * 8 + i] = f2bf(W[idx]);
    }
    __syncthreads();

    bf16x8 bfrag[18];
#pragma unroll
    for (int f = 0; f < 18; ++f)
        bfrag[f] = *(const bf16x8*)&WB[(f * 64 + lane) * 8];

    int nodeBase = blockIdx.x * 64 + w * 16;
    int arow = nodeBase + (lane & 15);
    int arowc = min(arow, NODES - 1);

    f32x4 acc[6];
#pragma unroll
    for (int n = 0; n < 6; ++n) { acc[n][0]=0.f; acc[n][1]=0.f; acc[n][2]=0.f; acc[n][3]=0.f; }

#pragma unroll
    for (int kb = 0; kb < 3; ++kb) {
        const float* ap = h + (size_t)arowc * HIDD + kb * 32 + (lane >> 4) * 8;
        float4 u0 = *(const float4*)ap;
        float4 u1 = *(const float4*)(ap + 4);
        bf16x8 af;
        af[0]=(short)f2bf(u0.x); af[1]=(short)f2bf(u0.y); af[2]=(short)f2bf(u0.z); af[3]=(short)f2bf(u0.w);
        af[4]=(short)f2bf(u1.x); af[5]=(short)f2bf(u1.y); af[6]=(short)f2bf(u1.z); af[7]=(short)f2bf(u1.w);
#pragma unroll
        for (int nt = 0; nt < 6; ++nt)
            acc[nt] = __builtin_amdgcn_mfma_f32_16x16x32_bf16(af, bfrag[kb * 6 + nt], acc[nt], 0, 0, 0);
    }

#pragma unroll
    for (int nt = 0; nt < 6; ++nt)
#pragma unroll
        for (int r = 0; r < 4; ++r)
            outT[w][(lane >> 4) * 4 + r][nt * 16 + (lane & 15)] = acc[nt][r];

    int nl = lane >> 2, head = lane & 3;
    int node = nodeBase + nl;
    if (node < NODES) {
        const float* row = &outT[w][nl][head * CHD];
        unsigned* orow = hpb + (size_t)node * (HIDD / 2) + head * (CHD / 2);
#pragma unroll
        for (int t = 0; t < CHD / 2; ++t)
            orow[t] = (unsigned)f2bf(row[2 * t]) | ((unsigned)f2bf(row[2 * t + 1]) << 16);
        const float* s = asrc + head * CHD;
        const float* d = adst + head * CHD;
        float sa = 0.f, da = 0.f;
#pragma unroll
        for (int j = 0; j < CHD; ++j) { sa = fmaf(row[j], s[j], sa); da = fmaf(row[j], d[j], da); }
        as_[node * NHEAD + head] = sa;
        ad_[node * NHEAD + head] = da;
    }
}

// ---------------- fused edge phase: 2 nodes/wave, chunk-pipelined; block-reduced pooled ----------------
// pooled: shard by blockIdx&3 (XCD locality); per-block LDS pre-reduction -> one atomic run
// per distinct graph per block (batch sorted -> typically 1-2 of 8 nodes' graphs).

__global__ __launch_bounds__(256) void k_edge(const int* __restrict__ off,
                                              const int* __restrict__ csr,
                                              const float* __restrict__ as_,
                                              const float* __restrict__ ad_,
                                              const unsigned* __restrict__ hpb,
                                              const float* __restrict__ bg,
                                              const float* __restrict__ gamma,
                                              const float* __restrict__ beta,
                                              const float* __restrict__ rm,
                                              const float* __restrict__ rv,
                                              float* __restrict__ h,
                                              const int* __restrict__ batch,
                                              float* __restrict__ pooled) {   // layer base, NSH shards
    __shared__ float plds[512];                     // per wave: 128 floats (2 nodes x 64)
    __shared__ float blk[8][HIDD];                  // 3 KB: per-node contributions
    __shared__ int   gblk[8];
    int tid = threadIdx.x;
    int lane = tid & 63;
    int w = tid >> 6;
    int n0 = __builtin_amdgcn_readfirstlane(blockIdx.x * 8 + w * 2);  // exact grid
    int n1 = n0 + 1;
    int beg0 = off[n0], end0 = off[n0 + 1], end1 = off[n0 + 2];
    int beg1 = end0;

    int hd = lane & 3, slot = lane >> 2;            // alpha role: edge slot x head
    float adv0 = ad_[n0 * NHEAD + hd];
    float adv1 = ad_[n1 * NHEAD + hd];
    const int hh = (lane < 48) ? (lane / 12) : 0;   // gather role: head of channel pair
    const bool gl = (lane < 48);
    const int wb = (tid & 192) * 2;                 // wave's plds region (w*128)

    float a00 = 0.f, a01 = 0.f, a10 = 0.f, a11 = 0.f, zA = 0.f, zB = 0.f;
    int ca = beg0, cb = beg1;
    int sA = 0, sB = 0;
    float evA = 0.f, evB = 0.f;
    if (ca < end0) { sA = csr[min(ca + slot, end0 - 1)]; evA = as_[sA * NHEAD + hd]; }
    if (cb < end1) { sB = csr[min(cb + slot, end1 - 1)]; evB = as_[sB * NHEAD + hd]; }

    while (ca < end0 || cb < end1) {
        int cntA = min(16, end0 - ca);
        int cntB = min(16, end1 - cb);
        if (cntA > 0) {
            float ev = evA + adv0;
            ev = ev > 0.f ? ev : 0.2f * ev;
            float p = (ca + slot < end0) ? __expf(ev) : 0.f;
            zA += p;
            plds[wb + lane] = p;
        }
        if (cntB > 0) {
            float ev = evB + adv1;
            ev = ev > 0.f ? ev : 0.2f * ev;
            float p = (cb + slot < end1) ? __expf(ev) : 0.f;
            zB += p;
            plds[wb + 64 + lane] = p;
        }
        int na = ca + (cntA > 0 ? 16 : 0);
        int nb = cb + (cntB > 0 ? 16 : 0);
        int sA2 = 0, sB2 = 0;
        float evA2 = 0.f, evB2 = 0.f;
        if (na < end0) { sA2 = csr[min(na + slot, end0 - 1)]; evA2 = as_[sA2 * NHEAD + hd]; }
        if (nb < end1) { sB2 = csr[min(nb + slot, end1 - 1)]; evB2 = as_[sB2 * NHEAD + hd]; }
        if (cntA > 0) {
#pragma unroll
            for (int j = 0; j < 16; ++j) {
                if (j < cntA) {
                    int sv = __builtin_amdgcn_readlane(sA, j * 4);
                    float al = plds[wb + j * 4 + hh];
                    if (gl) {
                        unsigned u = (hpb + (size_t)sv * (HIDD / 2))[lane];
                        a00 = fmaf(__uint_as_float(u << 16),         al, a00);
                        a01 = fmaf(__uint_as_float(u & 0xffff0000u), al, a01);
                    }
                }
            }
        }
        if (cntB > 0) {
#pragma unroll
            for (int j = 0; j < 16; ++j) {
                if (j < cntB) {
                    int sv = __builtin_amdgcn_readlane(sB, j * 4);
                    float al = plds[wb + 64 + j * 4 + hh];
                    if (gl) {
                        unsigned u = (hpb + (size_t)sv * (HIDD / 2))[lane];
                        a10 = fmaf(__uint_as_float(u << 16),         al, a10);
                        a11 = fmaf(__uint_as_float(u & 0xffff0000u), al, a11);
                    }
                }
            }
        }
        ca = na; cb = nb;
        sA = sA2; evA = evA2; sB = sB2; evB = evB2;
    }
#pragma unroll
    for (int o = 4; o < 64; o <<= 1) { zA += __shfl_xor(zA, o); zB += __shfl_xor(zB, o); }
    float za0 = rl_f(zA, 0), za1 = rl_f(zA, 1), za2 = rl_f(zA, 2), za3 = rl_f(zA, 3);
    float zb0 = rl_f(zB, 0), zb1 = rl_f(zB, 1), zb2 = rl_f(zB, 2), zb3 = rl_f(zB, 3);
    float zAl = (hh & 1) ? za1 : za0, zAh = (hh & 1) ? za3 : za2;
    float zBl = (hh & 1) ? zb1 : zb0, zBh = (hh & 1) ? zb3 : zb2;
    float zhA = (hh & 2) ? zAh : zAl;
    float zhB = (hh & 2) ? zBh : zBl;

    int g0 = batch[n0], g1 = batch[n1];
    if (gl) {
        float izA = 1.f / zhA, izB = 1.f / zhB;
        a00 *= izA; a01 *= izA; a10 *= izB; a11 *= izB;
        int ch0 = 2 * lane, ch1 = ch0 + 1;
        float hn00 = bnorm(a00, bg, rm, rv, gamma, beta, ch0);
        float hn01 = bnorm(a01, bg, rm, rv, gamma, beta, ch1);
        float hn10 = bnorm(a10, bg, rm, rv, gamma, beta, ch0);
        float hn11 = bnorm(a11, bg, rm, rv, gamma, beta, ch1);
        float2 hv0 = *(float2*)(h + (size_t)n0 * HIDD + ch0);
        float2 hv1 = *(float2*)(h + (size_t)n1 * HIDD + ch0);
        hv0.x += elu1(hn00); hv0.y += elu1(hn01);
        hv1.x += elu1(hn10); hv1.y += elu1(hn11);
        *(float2*)(h + (size_t)n0 * HIDD + ch0) = hv0;
        *(float2*)(h + (size_t)n1 * HIDD + ch0) = hv1;
        blk[w * 2 + 0][ch0] = hv0.x; blk[w * 2 + 0][ch1] = hv0.y;
        blk[w * 2 + 1][ch0] = hv1.x; blk[w * 2 + 1][ch1] = hv1.y;
    }
    if (lane == 0) { gblk[w * 2] = g0; gblk[w * 2 + 1] = g1; }
    __syncthreads();

    // block-level pooled reduction: one atomic run per distinct (sorted) graph id
    if (tid < HIDD) {
        float* pooledS = pooled + (size_t)(blockIdx.x & (NSH - 1)) * NGRF * HIDD;
        float acc = blk[0][tid];
        int g = gblk[0];
        for (int r = 1; r < 8; ++r) {
            int gr = gblk[r];
            float v = blk[r][tid];
            if (gr == g) acc += v;
            else { atomicAdd(&pooledS[g * HIDD + tid], acc); g = gr; acc = v; }
        }
        atomicAdd(&pooledS[g * HIDD + tid], acc);
    }
}

// ---------------- per-graph MLP head (sums NSH pooled shards) ----------------

__global__ __launch_bounds__(128) void k_head(const float* __restrict__ pooled,  // [L][NSH][G][96]
                                              const float* __restrict__ Wjk, const float* __restrict__ bjk,
                                              const float* __restrict__ Wh1, const float* __restrict__ bh1,
                                              const float* __restrict__ Wh2, const float* __restrict__ bh2,
                                              float* __restrict__ out) {
    __shared__ float pin[NLAY * HIDD];
    __shared__ float z1[HIDD];
    __shared__ float z2[HIDD];
    int g = blockIdx.x, tid = threadIdx.x;
    for (int idx = tid; idx < NLAY * HIDD; idx += blockDim.x) {
        int l = idx / HIDD, c = idx % HIDD;
        float a = 0.f;
#pragma unroll
        for (int s = 0; s < NSH; ++s)
            a += pooled[(((size_t)l * NSH + s) * NGRF + g) * HIDD + c];
        pin[idx] = a;
    }
    __syncthreads();
    for (int c = tid; c < HIDD; c += blockDim.x) {
        float a = bjk[c];
#pragma unroll 8
        for (int k = 0; k < NLAY * HIDD; ++k) a = fmaf(pin[k], Wjk[k * HIDD + c], a);
        z1[c] = elu1(a);
    }
    __syncthreads();
    for (int c = tid; c < HIDD; c += blockDim.x) {
        float a = bh1[c];
#pragma unroll 8
        for (int k = 0; k < HIDD; ++k) a = fmaf(z1[k], Wh1[k * HIDD + c], a);
        z2[c] = fmaxf(a, 0.f);
    }
    __syncthreads();
    if (tid < 64) {
        float a = 0.f;
        for (int k = tid; k < HIDD; k += 64) a = fmaf(z2[k], Wh2[k], a);
#pragma unroll
        for (int o = 32; o > 0; o >>= 1) a += __shfl_down(a, o);
        if (tid == 0) out[g] = a + bh2[0];
    }
}

extern "C" void kernel_launch(void* const* d_in, const int* in_sizes, int n_in,
                              void* d_out, int out_size, void* d_ws, size_t ws_size,
                              hipStream_t stream) {
    const float* x     = (const float*)d_in[0];
    const int*   ei    = (const int*)d_in[1];
    const int*   batch = (const int*)d_in[2];
    const float* W_in  = (const float*)d_in[3];
    const float* b_in  = (const float*)d_in[4];
    const float* Wg    = (const float*)d_in[5];
    const float* att_s = (const float*)d_in[6];
    const float* att_d = (const float*)d_in[7];
    const float* bg    = (const float*)d_in[8];
    const float* gamma = (const float*)d_in[9];
    const float* beta  = (const float*)d_in[10];
    const float* rm    = (const float*)d_in[11];
    const float* rv    = (const float*)d_in[12];
    const float* Wjk   = (const float*)d_in[13];
    const float* bjk   = (const float*)d_in[14];
    const float* Wh1   = (const float*)d_in[15];
    const float* bh1   = (const float*)d_in[16];
    const float* Wh2   = (const float*)d_in[17];
    const float* bh2   = (const float*)d_in[18];
    float* out = (float*)d_out;

    const int* S = ei;
    const int* Dd = ei + EDGES;

    // workspace layout
    float* ws = (float*)d_ws;
    float*    h      = ws;                               // N*96 f32
    float*    as_    = h    + (size_t)NODES * HIDD;      // N*4
    float*    ad_    = as_  + (size_t)NODES * NHEAD;     // N*4
    float*    pooled = ad_  + (size_t)NODES * NHEAD;     // L*NSH*G*96
    unsigned* hpb    = (unsigned*)(pooled + (size_t)NLAY * NSH * NGRF * HIDD); // N*48 (bf16x2)
    int*      off    = (int*)(hpb + (size_t)NODES * (HIDD / 2));  // N+2
    int*      cursor = off    + NODES + 2;               // N
    int*      csr    = cursor + NODES;                   // EP
    int*      cnt    = csr    + EP;                      // N
    int*      bsum   = cnt    + NODES;                   // NB

    hipMemsetAsync(cnt, 0, sizeof(int) * NODES, stream);

    const int TB = 256;
    int gE    = (EP + TB - 1) / TB;
    int gTile = (NODES + 63) / 64;    // 782 blocks, 64 nodes each
    int gEdge = NODES / 8;            // 6250 (exact: 8 nodes/block, 2 per wave)

    // CSR build (graph is identical across layers)
    k_count<<<gE, TB, 0, stream>>>(S, Dd, cnt);
    k_scan1<<<NB, 1024, 0, stream>>>(cnt, off, bsum);
    k_scan3m<<<NB, 1024, 0, stream>>>(off, bsum, cursor);
    k_scatter<<<gE, TB, 0, stream>>>(S, Dd, cursor, csr);

    // layer 0: all-MFMA fused input-proj + proj (also zeros sharded pooled)
    k_in0<<<gTile, TB, 0, stream>>>(x, W_in, b_in, Wg, att_s, att_d,
                                    h, hpb, as_, ad_, pooled);
    k_edge<<<gEdge, TB, 0, stream>>>(off, csr, as_, ad_, hpb,
                                     bg, gamma, beta, rm, rv, h, batch, pooled);

    for (int i = 1; i < NLAY; ++i) {
        k_proj<<<gTile, TB, 0, stream>>>(h, Wg + (size_t)i * HIDD * HIDD,
                                         att_s + i * NHEAD * CHD, att_d + i * NHEAD * CHD,
                                         hpb, as_, ad_);
        k_edge<<<gEdge, TB, 0, stream>>>(off, csr, as_, ad_, hpb,
                                         bg + i * HIDD, gamma + i * HIDD, beta + i * HIDD,
                                         rm + i * HIDD, rv + i * HIDD, h, batch,
                                         pooled + (size_t)i * NSH * NGRF * HIDD);
    }

    k_head<<<NGRF, 128, 0, stream>>>(pooled, Wjk, bjk, Wh1, bh1, Wh2, bh2, out);
}

// Round 22
// 455.455 us; speedup vs baseline: 1.0280x; 1.0280x over previous
//
#include <hip/hip_runtime.h>
#include <hip/hip_bf16.h>
#include <math.h>

#define NODES 50000
#define EDGES 800000
#define EP    850000      // EDGES + NODES self loops
#define INCH  64
#define HIDD  96
#define NHEAD 4
#define CHD   24
#define NLAY  4
#define NGRF  1024
#define BNEPS 1e-5f
#define NB    49          // ceil(NODES/1024)

typedef short  bf16x8 __attribute__((ext_vector_type(8)));   // 8 bf16 (4 VGPRs)
typedef float  f32x4  __attribute__((ext_vector_type(4)));   // MFMA accumulator

__device__ __forceinline__ float elu1(float v) { return v > 0.f ? v : __expf(v) - 1.f; }

__device__ __forceinline__ unsigned short f2bf(float f) {   // RNE, matches HW
    unsigned u = __float_as_uint(f);
    return (unsigned short)((u + 0x7fffu + ((u >> 16) & 1u)) >> 16);
}

__device__ __forceinline__ float rl_f(float v, int l) {     // readlane broadcast (uniform l)
    return __int_as_float(__builtin_amdgcn_readlane(__float_as_int(v), l));
}

__device__ __forceinline__ float bnorm(float a, const float* __restrict__ bg,
                                       const float* __restrict__ rm, const float* __restrict__ rv,
                                       const float* __restrict__ gamma, const float* __restrict__ beta,
                                       int ch) {
    float hn = a + bg[ch];
    return (hn - rm[ch]) / sqrtf(rv[ch] + BNEPS) * gamma[ch] + beta[ch];
}

__device__ __forceinline__ void edge_sd(int e, const int* __restrict__ S,
                                        const int* __restrict__ D, int& s, int& d) {
    if (e < EDGES) { s = S[e]; d = D[e]; } else { s = e - EDGES; d = s; }
}

// ---------------- CSR build ----------------

__global__ __launch_bounds__(256) void k_count(const int* __restrict__ S, const int* __restrict__ D,
                                               int* __restrict__ cnt) {
    int e = blockIdx.x * blockDim.x + threadIdx.x;
    if (e >= EP) return;
    int s, d; edge_sd(e, S, D, s, d);
    atomicAdd(&cnt[d], 1);
}

__global__ __launch_bounds__(1024) void k_scan1(const int* __restrict__ cnt,
                                                int* __restrict__ off, int* __restrict__ bsum) {
    __shared__ int sd[1024];
    int t = threadIdx.x;
    int i = blockIdx.x * 1024 + t;
    int v = (i < NODES) ? cnt[i] : 0;
    sd[t] = v; __syncthreads();
    for (int o = 1; o < 1024; o <<= 1) {
        int tv = (t >= o) ? sd[t - o] : 0;
        __syncthreads();
        sd[t] += tv; __syncthreads();
    }
    if (i < NODES) off[i] = sd[t] - v;           // exclusive within block
    if (t == 1023) bsum[blockIdx.x] = sd[1023];
}

__global__ __launch_bounds__(1024) void k_scan3m(int* __restrict__ off, const int* __restrict__ bsum,
                                                 int* __restrict__ cursor) {
    int carry = 0;
    for (int b = 0; b < blockIdx.x; ++b) carry += bsum[b];   // uniform s_loads
    int i = blockIdx.x * 1024 + threadIdx.x;
    if (i < NODES) {
        int o = off[i] + carry;
        off[i] = o;
        cursor[i] = o;
    }
    if (i == 0) off[NODES] = EP;
}

__global__ __launch_bounds__(256) void k_scatter(const int* __restrict__ S, const int* __restrict__ D,
                                                 int* __restrict__ cursor, int* __restrict__ csr_src) {
    int e = blockIdx.x * blockDim.x + threadIdx.x;
    if (e >= EP) return;
    int s, d; edge_sd(e, S, D, s, d);
    int pos = atomicAdd(&cursor[d], 1);
    csr_src[pos] = s;
}

// ---------------- layer 0, all-MFMA: h = elu(x@W_in + b) ; hp0 = h@Wg0 (+att dots) ----------------

__global__ __launch_bounds__(256) void k_in0(const float* __restrict__ x,
                                             const float* __restrict__ W_in,
                                             const float* __restrict__ b_in,
                                             const float* __restrict__ Wg0,
                                             const float* __restrict__ asrc,
                                             const float* __restrict__ adst,
                                             float* __restrict__ h,
                                             unsigned* __restrict__ hpb,
                                             float* __restrict__ as_,
                                             float* __restrict__ ad_,
                                             float* __restrict__ pooled_all) {
    __shared__ __align__(16) unsigned short WB[3 * 6 * 64 * 8];  // 18 KB (W_in uses 12 KB)
    __shared__ float outT[4][16][97];                            // 24.25 KB, wave-private tiles
    int tid = threadIdx.x;
    int lane = tid & 63;
    int w = tid >> 6;

    // zero pooled (grid-stride; completes before k_edge in stream order)
    for (size_t i = (size_t)blockIdx.x * 256 + tid; i < (size_t)NLAY * NGRF * HIDD;
         i += (size_t)gridDim.x * 256)
        pooled_all[i] = 0.f;

    // stage W_in -> fragment layout (K=64 -> frags 0..11)
    for (int idx = tid; idx < INCH * HIDD; idx += 256) {
        int k = idx / HIDD, col = idx - k * HIDD;
        int kb = k >> 5, lg = (k & 31) >> 3, i = k & 7;
        int nt = col >> 4, cl = col & 15;
        WB[(((kb * 6) + nt) * 64 + (lg * 16 + cl)) * 8 + i] = f2bf(W_in[idx]);
    }
    __syncthreads();

    bf16x8 bf1[12];
#pragma unroll
    for (int f = 0; f < 12; ++f)
        bf1[f] = *(const bf16x8*)&WB[(f * 64 + lane) * 8];

    int nodeBase = blockIdx.x * 64 + w * 16;
    int arow = nodeBase + (lane & 15);
    int arowc = min(arow, NODES - 1);

    // ---- stage 1: x @ W_in ----
    {
        f32x4 acc[6];
#pragma unroll
        for (int n = 0; n < 6; ++n) { acc[n][0]=0.f; acc[n][1]=0.f; acc[n][2]=0.f; acc[n][3]=0.f; }
#pragma unroll
        for (int kb = 0; kb < 2; ++kb) {
            const float* ap = x + (size_t)arowc * INCH + kb * 32 + (lane >> 4) * 8;
            float4 u0 = *(const float4*)ap;
            float4 u1 = *(const float4*)(ap + 4);
            bf16x8 af;
            af[0]=(short)f2bf(u0.x); af[1]=(short)f2bf(u0.y); af[2]=(short)f2bf(u0.z); af[3]=(short)f2bf(u0.w);
            af[4]=(short)f2bf(u1.x); af[5]=(short)f2bf(u1.y); af[6]=(short)f2bf(u1.z); af[7]=(short)f2bf(u1.w);
#pragma unroll
            for (int nt = 0; nt < 6; ++nt)
                acc[nt] = __builtin_amdgcn_mfma_f32_16x16x32_bf16(af, bf1[kb * 6 + nt], acc[nt], 0, 0, 0);
        }
        // bias + elu in-register, dump to own outT region
#pragma unroll
        for (int nt = 0; nt < 6; ++nt) {
            int col = nt * 16 + (lane & 15);
            float b = b_in[col];
#pragma unroll
            for (int r = 0; r < 4; ++r)
                outT[w][(lane >> 4) * 4 + r][col] = elu1(acc[nt][r] + b);
        }
    }
    __syncthreads();                    // all waves done reading WB (bf1 in regs)

    // restage Wg0 -> fragment layout (frags 0..17)
    for (int idx = tid; idx < HIDD * HIDD; idx += 256) {
        int k = idx / HIDD, col = idx - k * HIDD;
        int kb = k >> 5, lg = (k & 31) >> 3, i = k & 7;
        int nt = col >> 4, cl = col & 15;
        WB[(((kb * 6) + nt) * 64 + (lg * 16 + cl)) * 8 + i] = f2bf(Wg0[idx]);
    }
    __syncthreads();

    bf16x8 bf2[18];
#pragma unroll
    for (int f = 0; f < 18; ++f)
        bf2[f] = *(const bf16x8*)&WB[(f * 64 + lane) * 8];

    // write h to global (coalesced; own outT region, wave-ordered)
    {
        int nl = lane >> 2, part = lane & 3;
        int noden = nodeBase + nl;
        if (noden < NODES) {
            float* hw = h + (size_t)noden * HIDD + part * 24;
            const float* row = &outT[w][nl][part * 24];
#pragma unroll
            for (int t = 0; t < 6; ++t)
                ((float4*)hw)[t] = *(const float4*)&row[t * 4];
        }
    }

    // ---- stage 2: h @ Wg0 (A from own outT region) ----
    f32x4 acc2[6];
#pragma unroll
    for (int n = 0; n < 6; ++n) { acc2[n][0]=0.f; acc2[n][1]=0.f; acc2[n][2]=0.f; acc2[n][3]=0.f; }
#pragma unroll
    for (int kb = 0; kb < 3; ++kb) {
        const float* ap = &outT[w][lane & 15][kb * 32 + (lane >> 4) * 8];
        bf16x8 af;
#pragma unroll
        for (int i = 0; i < 8; ++i) af[i] = (short)f2bf(ap[i]);
#pragma unroll
        for (int nt = 0; nt < 6; ++nt)
            acc2[nt] = __builtin_amdgcn_mfma_f32_16x16x32_bf16(af, bf2[kb * 6 + nt], acc2[nt], 0, 0, 0);
    }
    // dump (own region; program-ordered after the reads above)
#pragma unroll
    for (int nt = 0; nt < 6; ++nt)
#pragma unroll
        for (int r = 0; r < 4; ++r)
            outT[w][(lane >> 4) * 4 + r][nt * 16 + (lane & 15)] = acc2[nt][r];

    // epilogue: pack + attention dots (own region)
    int nl = lane >> 2, head = lane & 3;
    int node = nodeBase + nl;
    if (node < NODES) {
        const float* row = &outT[w][nl][head * CHD];
        unsigned* orow = hpb + (size_t)node * (HIDD / 2) + head * (CHD / 2);
#pragma unroll
        for (int t = 0; t < CHD / 2; ++t)
            orow[t] = (unsigned)f2bf(row[2 * t]) | ((unsigned)f2bf(row[2 * t + 1]) << 16);
        const float* s = asrc + head * CHD;
        const float* d = adst + head * CHD;
        float sa = 0.f, da = 0.f;
#pragma unroll
        for (int j = 0; j < CHD; ++j) { sa = fmaf(row[j], s[j], sa); da = fmaf(row[j], d[j], da); }
        as_[node * NHEAD + head] = sa;
        ad_[node * NHEAD + head] = da;
    }
}

// ---------------- per-layer proj via MFMA (layers 1..3) ----------------

__global__ __launch_bounds__(256) void k_proj(const float* __restrict__ h,
                                              const float* __restrict__ W,
                                              const float* __restrict__ asrc,
                                              const float* __restrict__ adst,
                                              unsigned* __restrict__ hpb,   // [N][48] packed bf16x2
                                              float* __restrict__ as_,
                                              float* __restrict__ ad_) {
    __shared__ __align__(16) unsigned short WB[3 * 6 * 64 * 8];  // 18 KB, fragment layout
    __shared__ float outT[4][16][97];                            // 24.25 KB, padded rows
    int tid = threadIdx.x;
    int lane = tid & 63;
    int w = tid >> 6;

    for (int idx = tid; idx < HIDD * HIDD; idx += 256) {
        int k = idx / HIDD, col = idx - k * HIDD;
        int kb = k >> 5, lg = (k & 31) >> 3, i = k & 7;
        int nt = col >> 4, cl = col & 15;
        WB[(((kb * 6) + nt) * 64 + (lg * 16 + cl)) * 8 + i] = f2bf(W[idx]);
    }
    __syncthreads();

    bf16x8 bfrag[18];
#pragma unroll
    for (int f = 0; f < 18; ++f)
        bfrag[f] = *(const bf16x8*)&WB[(f * 64 + lane) * 8];

    int nodeBase = blockIdx.x * 64 + w * 16;
    int arow = nodeBase + (lane & 15);
    int arowc = min(arow, NODES - 1);

    f32x4 acc[6];
#pragma unroll
    for (int n = 0; n < 6; ++n) { acc[n][0]=0.f; acc[n][1]=0.f; acc[n][2]=0.f; acc[n][3]=0.f; }

#pragma unroll
    for (int kb = 0; kb < 3; ++kb) {
        const float* ap = h + (size_t)arowc * HIDD + kb * 32 + (lane >> 4) * 8;
        float4 u0 = *(const float4*)ap;
        float4 u1 = *(const float4*)(ap + 4);
        bf16x8 af;
        af[0]=(short)f2bf(u0.x); af[1]=(short)f2bf(u0.y); af[2]=(short)f2bf(u0.z); af[3]=(short)f2bf(u0.w);
        af[4]=(short)f2bf(u1.x); af[5]=(short)f2bf(u1.y); af[6]=(short)f2bf(u1.z); af[7]=(short)f2bf(u1.w);
#pragma unroll
        for (int nt = 0; nt < 6; ++nt)
            acc[nt] = __builtin_amdgcn_mfma_f32_16x16x32_bf16(af, bfrag[kb * 6 + nt], acc[nt], 0, 0, 0);
    }

#pragma unroll
    for (int nt = 0; nt < 6; ++nt)
#pragma unroll
        for (int r = 0; r < 4; ++r)
            outT[w][(lane >> 4) * 4 + r][nt * 16 + (lane & 15)] = acc[nt][r];

    int nl = lane >> 2, head = lane & 3;
    int node = nodeBase + nl;
    if (node < NODES) {
        const float* row = &outT[w][nl][head * CHD];
        unsigned* orow = hpb + (size_t)node * (HIDD / 2) + head * (CHD / 2);
#pragma unroll
        for (int t = 0; t < CHD / 2; ++t)
            orow[t] = (unsigned)f2bf(row[2 * t]) | ((unsigned)f2bf(row[2 * t + 1]) << 16);
        const float* s = asrc + head * CHD;
        const float* d = adst + head * CHD;
        float sa = 0.f, da = 0.f;
#pragma unroll
        for (int j = 0; j < CHD; ++j) { sa = fmaf(row[j], s[j], sa); da = fmaf(row[j], d[j], da); }
        as_[node * NHEAD + head] = sa;
        ad_[node * NHEAD + head] = da;
    }
}

// ---------------- fused edge phase: 2 nodes/wave, uniform guards, chunk-pipelined ----------------

__global__ __launch_bounds__(256) void k_edge(const int* __restrict__ off,
                                              const int* __restrict__ csr,
                                              const float* __restrict__ as_,
                                              const float* __restrict__ ad_,
                                              const unsigned* __restrict__ hpb,
                                              const float* __restrict__ bg,
                                              const float* __restrict__ gamma,
                                              const float* __restrict__ beta,
                                              const float* __restrict__ rm,
                                              const float* __restrict__ rv,
                                              float* __restrict__ h,
                                              const int* __restrict__ batch,
                                              float* __restrict__ pooled) {
    __shared__ float plds[512];                     // per wave: 128 floats (2 nodes x 64)
    int tid = threadIdx.x;
    int lane = tid & 63;
    int n0 = __builtin_amdgcn_readfirstlane(blockIdx.x * 8 + (tid >> 6) * 2);  // exact grid
    int n1 = n0 + 1;
    int beg0 = off[n0], end0 = off[n0 + 1], end1 = off[n0 + 2];
    int beg1 = end0;

    int hd = lane & 3, slot = lane >> 2;            // alpha role: edge slot x head
    float adv0 = ad_[n0 * NHEAD + hd];
    float adv1 = ad_[n1 * NHEAD + hd];
    const int hh = (lane < 48) ? (lane / 12) : 0;   // gather role: head of channel pair
    const bool gl = (lane < 48);
    const int wb = (tid & 192) * 2;                 // wave's plds region (w*128)

    float a00 = 0.f, a01 = 0.f, a10 = 0.f, a11 = 0.f, zA = 0.f, zB = 0.f;
    int ca = beg0, cb = beg1;
    int sA = 0, sB = 0;
    float evA = 0.f, evB = 0.f;
    if (ca < end0) { sA = csr[min(ca + slot, end0 - 1)]; evA = as_[sA * NHEAD + hd]; }
    if (cb < end1) { sB = csr[min(cb + slot, end1 - 1)]; evB = as_[sB * NHEAD + hd]; }

    while (ca < end0 || cb < end1) {
        int cntA = min(16, end0 - ca);
        int cntB = min(16, end1 - cb);
        if (cntA > 0) {
            float ev = evA + adv0;
            ev = ev > 0.f ? ev : 0.2f * ev;
            float p = (ca + slot < end0) ? __expf(ev) : 0.f;
            zA += p;
            plds[wb + lane] = p;
        }
        if (cntB > 0) {
            float ev = evB + adv1;
            ev = ev > 0.f ? ev : 0.2f * ev;
            float p = (cb + slot < end1) ? __expf(ev) : 0.f;
            zB += p;
            plds[wb + 64 + lane] = p;
        }
        int na = ca + (cntA > 0 ? 16 : 0);
        int nb = cb + (cntB > 0 ? 16 : 0);
        int sA2 = 0, sB2 = 0;
        float evA2 = 0.f, evB2 = 0.f;
        if (na < end0) { sA2 = csr[min(na + slot, end0 - 1)]; evA2 = as_[sA2 * NHEAD + hd]; }
        if (nb < end1) { sB2 = csr[min(nb + slot, end1 - 1)]; evB2 = as_[sB2 * NHEAD + hd]; }
        if (cntA > 0) {
#pragma unroll
            for (int j = 0; j < 16; ++j) {
                if (j < cntA) {
                    int sv = __builtin_amdgcn_readlane(sA, j * 4);
                    float al = plds[wb + j * 4 + hh];
                    if (gl) {
                        unsigned u = (hpb + (size_t)sv * (HIDD / 2))[lane];
                        a00 = fmaf(__uint_as_float(u << 16),         al, a00);
                        a01 = fmaf(__uint_as_float(u & 0xffff0000u), al, a01);
                    }
                }
            }
        }
        if (cntB > 0) {
#pragma unroll
            for (int j = 0; j < 16; ++j) {
                if (j < cntB) {
                    int sv = __builtin_amdgcn_readlane(sB, j * 4);
                    float al = plds[wb + 64 + j * 4 + hh];
                    if (gl) {
                        unsigned u = (hpb + (size_t)sv * (HIDD / 2))[lane];
                        a10 = fmaf(__uint_as_float(u << 16),         al, a10);
                        a11 = fmaf(__uint_as_float(u & 0xffff0000u), al, a11);
                    }
                }
            }
        }
        ca = na; cb = nb;
        sA = sA2; evA = evA2; sB = sB2; evB = evB2;
    }
#pragma unroll
    for (int o = 4; o < 64; o <<= 1) { zA += __shfl_xor(zA, o); zB += __shfl_xor(zB, o); }
    float za0 = rl_f(zA, 0), za1 = rl_f(zA, 1), za2 = rl_f(zA, 2), za3 = rl_f(zA, 3);
    float zb0 = rl_f(zB, 0), zb1 = rl_f(zB, 1), zb2 = rl_f(zB, 2), zb3 = rl_f(zB, 3);
    float zAl = (hh & 1) ? za1 : za0, zAh = (hh & 1) ? za3 : za2;
    float zBl = (hh & 1) ? zb1 : zb0, zBh = (hh & 1) ? zb3 : zb2;
    float zhA = (hh & 2) ? zAh : zAl;
    float zhB = (hh & 2) ? zBh : zBl;

    int g0 = batch[n0], g1 = batch[n1];
    if (gl) {
        float izA = 1.f / zhA, izB = 1.f / zhB;
        a00 *= izA; a01 *= izA; a10 *= izB; a11 *= izB;
        int ch0 = 2 * lane, ch1 = ch0 + 1;
        float hn00 = bnorm(a00, bg, rm, rv, gamma, beta, ch0);
        float hn01 = bnorm(a01, bg, rm, rv, gamma, beta, ch1);
        float hn10 = bnorm(a10, bg, rm, rv, gamma, beta, ch0);
        float hn11 = bnorm(a11, bg, rm, rv, gamma, beta, ch1);
        float2 hv0 = *(float2*)(h + (size_t)n0 * HIDD + ch0);
        float2 hv1 = *(float2*)(h + (size_t)n1 * HIDD + ch0);
        hv0.x += elu1(hn00); hv0.y += elu1(hn01);
        hv1.x += elu1(hn10); hv1.y += elu1(hn11);
        *(float2*)(h + (size_t)n0 * HIDD + ch0) = hv0;
        *(float2*)(h + (size_t)n1 * HIDD + ch0) = hv1;
        if (g0 == g1) {
            atomicAdd(&pooled[g0 * HIDD + ch0], hv0.x + hv1.x);
            atomicAdd(&pooled[g0 * HIDD + ch1], hv0.y + hv1.y);
        } else {
            atomicAdd(&pooled[g0 * HIDD + ch0], hv0.x);
            atomicAdd(&pooled[g0 * HIDD + ch1], hv0.y);
            atomicAdd(&pooled[g1 * HIDD + ch0], hv1.x);
            atomicAdd(&pooled[g1 * HIDD + ch1], hv1.y);
        }
    }
}

// ---------------- per-graph MLP head ----------------

__global__ __launch_bounds__(128) void k_head(const float* __restrict__ pooled,
                                              const float* __restrict__ Wjk, const float* __restrict__ bjk,
                                              const float* __restrict__ Wh1, const float* __restrict__ bh1,
                                              const float* __restrict__ Wh2, const float* __restrict__ bh2,
                                              float* __restrict__ out) {
    __shared__ float pin[NLAY * HIDD];
    __shared__ float z1[HIDD];
    __shared__ float z2[HIDD];
    int g = blockIdx.x, tid = threadIdx.x;
    for (int idx = tid; idx < NLAY * HIDD; idx += blockDim.x) {
        int l = idx / HIDD, c = idx % HIDD;
        pin[idx] = pooled[(size_t)l * NGRF * HIDD + (size_t)g * HIDD + c];
    }
    __syncthreads();
    for (int c = tid; c < HIDD; c += blockDim.x) {
        float a = bjk[c];
#pragma unroll 8
        for (int k = 0; k < NLAY * HIDD; ++k) a = fmaf(pin[k], Wjk[k * HIDD + c], a);
        z1[c] = elu1(a);
    }
    __syncthreads();
    for (int c = tid; c < HIDD; c += blockDim.x) {
        float a = bh1[c];
#pragma unroll 8
        for (int k = 0; k < HIDD; ++k) a = fmaf(z1[k], Wh1[k * HIDD + c], a);
        z2[c] = fmaxf(a, 0.f);
    }
    __syncthreads();
    if (tid < 64) {
        float a = 0.f;
        for (int k = tid; k < HIDD; k += 64) a = fmaf(z2[k], Wh2[k], a);
#pragma unroll
        for (int o = 32; o > 0; o >>= 1) a += __shfl_down(a, o);
        if (tid == 0) out[g] = a + bh2[0];
    }
}

extern "C" void kernel_launch(void* const* d_in, const int* in_sizes, int n_in,
                              void* d_out, int out_size, void* d_ws, size_t ws_size,
                              hipStream_t stream) {
    const float* x     = (const float*)d_in[0];
    const int*   ei    = (const int*)d_in[1];
    const int*   batch = (const int*)d_in[2];
    const float* W_in  = (const float*)d_in[3];
    const float* b_in  = (const float*)d_in[4];
    const float* Wg    = (const float*)d_in[5];
    const float* att_s = (const float*)d_in[6];
    const float* att_d = (const float*)d_in[7];
    const float* bg    = (const float*)d_in[8];
    const float* gamma = (const float*)d_in[9];
    const float* beta  = (const float*)d_in[10];
    const float* rm    = (const float*)d_in[11];
    const float* rv    = (const float*)d_in[12];
    const float* Wjk   = (const float*)d_in[13];
    const float* bjk   = (const float*)d_in[14];
    const float* Wh1   = (const float*)d_in[15];
    const float* bh1   = (const float*)d_in[16];
    const float* Wh2   = (const float*)d_in[17];
    const float* bh2   = (const float*)d_in[18];
    float* out = (float*)d_out;

    const int* S = ei;
    const int* Dd = ei + EDGES;

    // workspace layout
    float* ws = (float*)d_ws;
    float*    h      = ws;                               // N*96 f32
    float*    as_    = h    + (size_t)NODES * HIDD;      // N*4
    float*    ad_    = as_  + (size_t)NODES * NHEAD;     // N*4
    float*    pooled = ad_  + (size_t)NODES * NHEAD;     // L*G*96
    unsigned* hpb    = (unsigned*)(pooled + (size_t)NLAY * NGRF * HIDD); // N*48 (bf16x2)
    int*      off    = (int*)(hpb + (size_t)NODES * (HIDD / 2));  // N+2
    int*      cursor = off    + NODES + 2;               // N
    int*      csr    = cursor + NODES;                   // EP
    int*      cnt    = csr    + EP;                      // N
    int*      bsum   = cnt    + NODES;                   // NB

    hipMemsetAsync(cnt, 0, sizeof(int) * NODES, stream);

    const int TB = 256;
    int gE    = (EP + TB - 1) / TB;
    int gTile = (NODES + 63) / 64;    // 782 blocks, 64 nodes each
    int gEdge = NODES / 8;            // 6250 (exact: 8 nodes/block, 2 per wave)

    // CSR build (graph is identical across layers)
    k_count<<<gE, TB, 0, stream>>>(S, Dd, cnt);
    k_scan1<<<NB, 1024, 0, stream>>>(cnt, off, bsum);
    k_scan3m<<<NB, 1024, 0, stream>>>(off, bsum, cursor);
    k_scatter<<<gE, TB, 0, stream>>>(S, Dd, cursor, csr);

    // layer 0: all-MFMA fused input-proj + proj (also zeros pooled)
    k_in0<<<gTile, TB, 0, stream>>>(x, W_in, b_in, Wg, att_s, att_d,
                                    h, hpb, as_, ad_, pooled);
    k_edge<<<gEdge, TB, 0, stream>>>(off, csr, as_, ad_, hpb,
                                     bg, gamma, beta, rm, rv, h, batch, pooled);

    for (int i = 1; i < NLAY; ++i) {
        k_proj<<<gTile, TB, 0, stream>>>(h, Wg + (size_t)i * HIDD * HIDD,
                                         att_s + i * NHEAD * CHD, att_d + i * NHEAD * CHD,
                                         hpb, as_, ad_);
        k_edge<<<gEdge, TB, 0, stream>>>(off, csr, as_, ad_, hpb,
                                         bg + i * HIDD, gamma + i * HIDD, beta + i * HIDD,
                                         rm + i * HIDD, rv + i * HIDD, h, batch,
                                         pooled + (size_t)i * NGRF * HIDD);
    }

    k_head<<<NGRF, 128, 0, stream>>>(pooled, Wjk, bjk, Wh1, bh1, Wh2, bh2, out);
}